// Round 3
// baseline (834.291 us; speedup 1.0000x reference)
//
#include <hip/hip_runtime.h>

static constexpr int NN   = 100000;   // nodes
static constexpr int NE   = 1600000;  // edges (without self loops)
static constexpr int ET   = NE + NN;  // edges + self loops
static constexpr int NG   = 512;      // graphs
static constexpr int INF_ = 16;
static constexpr int HID  = 64;
static constexpr int BKT_SH = 7;                       // 128 nodes / bucket
static constexpr int NBKT = (NN + 127) / 128;          // 782 buckets
#define NEG_SLOPE 0.2f

__device__ __forceinline__ float lrelu(float x) { return x > 0.f ? x : NEG_SLOPE * x; }

// ---------- layer-1 node transform: h = relu(x) @ W1, a_src/a_dst dots ----------
__global__ __launch_bounds__(256) void k_node1(
    const float* __restrict__ x, const float* __restrict__ W,
    const float* __restrict__ atts, const float* __restrict__ attd,
    float* __restrict__ h, float* __restrict__ a_s, float* __restrict__ a_d)
{
  __shared__ float Ws[INF_][HID];
  __shared__ float xs[4][INF_];
  const int tid = threadIdx.x;
  for (int i = tid; i < INF_ * HID; i += 256) Ws[i / HID][i % HID] = W[i];
  const int wv = tid >> 6, ln = tid & 63;
  const int n = blockIdx.x * 4 + wv;
  if (ln < INF_) {
    float v = x[n * INF_ + ln];
    xs[wv][ln] = v > 0.f ? v : 0.f;
  }
  __syncthreads();
  float acc = 0.f;
#pragma unroll
  for (int k = 0; k < INF_; ++k) acc += xs[wv][k] * Ws[k][ln];
  h[n * HID + ln] = acc;
  float as = acc * atts[ln], ad = acc * attd[ln];
#pragma unroll
  for (int o = 32; o > 0; o >>= 1) { as += __shfl_xor(as, o); ad += __shfl_xor(ad, o); }
  if (ln == 0) { a_s[n] = as; a_d[n] = ad; }
}

// ---------- layer-2 node transform: h2 = act1 @ W2 (act1 already relu'd) ----------
__global__ __launch_bounds__(256) void k_node2(
    const float* __restrict__ act, const float* __restrict__ W,
    const float* __restrict__ atts, const float* __restrict__ attd,
    float* __restrict__ h, float* __restrict__ a_s, float* __restrict__ a_d)
{
  __shared__ float Ws[HID][HID];   // 16 KB
  __shared__ float xs[4][HID];
  const int tid = threadIdx.x;
  for (int i = tid; i < HID * HID; i += 256) Ws[i / HID][i % HID] = W[i];
  const int wv = tid >> 6, ln = tid & 63;
  const int n = blockIdx.x * 4 + wv;
  xs[wv][ln] = act[n * HID + ln];
  __syncthreads();
  float acc = 0.f;
#pragma unroll
  for (int k = 0; k < HID; ++k) acc += xs[wv][k] * Ws[k][ln];
  h[n * HID + ln] = acc;
  float as = acc * atts[ln], ad = acc * attd[ln];
#pragma unroll
  for (int o = 32; o > 0; o >>= 1) { as += __shfl_xor(as, o); ad += __shfl_xor(ad, o); }
  if (ln == 0) { a_s[n] = as; a_d[n] = ad; }
}

// ---------- bucket histogram (LDS-staged) ----------
__global__ __launch_bounds__(256) void k_bhist(const int* __restrict__ ei,
                                               unsigned* __restrict__ bcnt)
{
  __shared__ unsigned lc[NBKT];
  for (int i = threadIdx.x; i < NBKT; i += 256) lc[i] = 0;
  __syncthreads();
  for (int e = blockIdx.x * 256 + threadIdx.x; e < ET; e += gridDim.x * 256) {
    int d = (e < NE) ? ei[NE + e] : e - NE;
    atomicAdd(&lc[d >> BKT_SH], 1u);
  }
  __syncthreads();
  for (int i = threadIdx.x; i < NBKT; i += 256)
    if (lc[i]) atomicAdd(&bcnt[i], lc[i]);
}

// ---------- exclusive scan of bucket counts (single wave) + cursor init ----------
__global__ __launch_bounds__(64) void k_bscan(const unsigned* __restrict__ bcnt,
                                              unsigned* __restrict__ boff,
                                              unsigned* __restrict__ bcur)
{
  const int ln = threadIdx.x;
  unsigned carry = 0;
  for (int base = 0; base < NBKT; base += 64) {
    int i = base + ln;
    unsigned c = (i < NBKT) ? bcnt[i] : 0;
    unsigned v = c;
#pragma unroll
    for (int o = 1; o < 64; o <<= 1) { unsigned tv = __shfl_up(v, o); if (ln >= o) v += tv; }
    if (i < NBKT) { boff[i] = carry + v - c; bcur[i] = carry + v - c; }
    carry += __shfl(v, 63);
  }
}

// ---------- coarse scatter: (src,dst) pairs into bucket-ordered staging ----------
__global__ __launch_bounds__(256) void k_bscatter(const int* __restrict__ ei,
                                                  unsigned* __restrict__ bcur,
                                                  int2* __restrict__ pairs)
{
  int e = blockIdx.x * 256 + threadIdx.x;
  if (e >= ET) return;
  int s, d;
  if (e < NE) { s = ei[e]; d = ei[NE + e]; } else { s = d = e - NE; }
  unsigned pos = atomicAdd(&bcur[d >> BKT_SH], 1u);
  pairs[pos] = make_int2(s, d);
}

// ---------- per-bucket fine CSR build (all in LDS, one block per bucket) ----------
__global__ __launch_bounds__(256) void k_bcsr(const int2* __restrict__ pairs,
                                              const unsigned* __restrict__ bcnt,
                                              const unsigned* __restrict__ boff,
                                              unsigned* __restrict__ rowptr,
                                              unsigned* __restrict__ deg,
                                              int* __restrict__ es)
{
  __shared__ unsigned cnt[128], cur[128], wtot[2];
  const int b = blockIdx.x, t = threadIdx.x;
  const unsigned base = boff[b], m = bcnt[b];
  if (t < 128) cnt[t] = 0;
  __syncthreads();
  for (unsigned j = t; j < m; j += 256)
    atomicAdd(&cnt[pairs[base + j].y & 127], 1u);
  __syncthreads();
  unsigned c = 0, v = 0;
  if (t < 128) {
    c = cnt[t]; v = c;
    const int ln = t & 63;
#pragma unroll
    for (int o = 1; o < 64; o <<= 1) { unsigned tv = __shfl_up(v, o); if (ln >= o) v += tv; }
    if (ln == 63) wtot[t >> 6] = v;
  }
  __syncthreads();
  if (t < 128) {
    unsigned excl = v - c + ((t >= 64) ? wtot[0] : 0);
    cur[t] = excl;
    int node = (b << BKT_SH) + t;
    if (node < NN) { rowptr[node] = base + excl; deg[node] = c; }
  }
  __syncthreads();
  for (unsigned j = t; j < m; j += 256) {
    int2 p = pairs[base + j];
    unsigned pos = atomicAdd(&cur[p.y & 127], 1u);
    es[base + pos] = p.x;
  }
}

// ---------- gather-style GAT aggregate: wave per dst node, no atomics ----------
__global__ __launch_bounds__(256) void k_gather(
    const int* __restrict__ es, const unsigned* __restrict__ rowptr,
    const unsigned* __restrict__ deg, const float* __restrict__ a_s,
    const float* __restrict__ a_d, const float* __restrict__ h,
    const float* __restrict__ bias, float* __restrict__ act)
{
  const int wv = threadIdx.x >> 6, ln = threadIdx.x & 63;
  const int n = blockIdx.x * 4 + wv;
  const unsigned beg = rowptr[n];
  const unsigned end = beg + deg[n];
  const float ad = a_d[n];
  // phase 1: segment max (lane-parallel over edges)
  float m = -1e30f;
  for (unsigned j = beg + ln; j < end; j += 64) {
    int s = es[j];
    m = fmaxf(m, lrelu(a_s[s] + ad));
  }
#pragma unroll
  for (int o = 32; o > 0; o >>= 1) m = fmaxf(m, __shfl_xor(m, o));
  // phase 2: serial over edges, lane-parallel over features
  float acc = 0.f, den = 0.f;
  unsigned j = beg;
  for (; j + 1 < end; j += 2) {
    int s0 = es[j], s1 = es[j + 1];
    float e0 = __expf(lrelu(a_s[s0] + ad) - m);
    float e1 = __expf(lrelu(a_s[s1] + ad) - m);
    float h0 = h[(size_t)s0 * HID + ln];
    float h1 = h[(size_t)s1 * HID + ln];
    den += e0 + e1;
    acc += h0 * e0 + h1 * e1;
  }
  if (j < end) {
    int s0 = es[j];
    float e0 = __expf(lrelu(a_s[s0] + ad) - m);
    den += e0;
    acc += h[(size_t)s0 * HID + ln] * e0;
  }
  float v = acc / (den + 1e-16f) + bias[ln];
  act[n * HID + ln] = v > 0.f ? v : 0.f;
}

// ---------- pooling: per-graph max/sum over finalized act2 ----------
__global__ __launch_bounds__(256) void k_pool(
    const float* __restrict__ act, const int* __restrict__ batch,
    unsigned* __restrict__ gmax, float* __restrict__ gsum, unsigned* __restrict__ cnt)
{
  const int wv = threadIdx.x >> 6, ln = threadIdx.x & 63;
  const int base = (blockIdx.x * 4 + wv) * 64;
  if (base >= NN) return;
  const int end = min(NN, base + 64);
  float rmax = 0.f, rsum = 0.f;
  int cg = batch[base], run = 0;
  for (int n = base; n < end; ++n) {
    int g = batch[n];
    if (g != cg) {
      atomicMax(&gmax[cg * HID + ln], __float_as_uint(rmax));  // relu -> >=0
      unsafeAtomicAdd(&gsum[cg * HID + ln], rsum);
      if (ln == 0) atomicAdd(&cnt[cg], (unsigned)run);
      rmax = 0.f; rsum = 0.f; run = 0; cg = g;
    }
    float v = act[n * HID + ln];
    rmax = fmaxf(rmax, v); rsum += v; ++run;
  }
  atomicMax(&gmax[cg * HID + ln], __float_as_uint(rmax));
  unsafeAtomicAdd(&gsum[cg * HID + ln], rsum);
  if (ln == 0) atomicAdd(&cnt[cg], (unsigned)run);
}

// ---------- head: [gmax | gmean] @ fc_w + fc_b ----------
__global__ __launch_bounds__(256) void k_final(
    const unsigned* __restrict__ gmax, const float* __restrict__ gsum,
    const unsigned* __restrict__ cnt, const float* __restrict__ fcw,
    const float* __restrict__ fcb, float* __restrict__ out)
{
  const int wv = threadIdx.x >> 6, ln = threadIdx.x & 63;
  const int g = blockIdx.x * 4 + wv;
  if (g >= NG) return;
  float c = (float)cnt[g];
  float mx = __uint_as_float(gmax[g * HID + ln]);
  float mean = gsum[g * HID + ln] / fmaxf(c, 1.f);
  float v = mx * fcw[ln] + mean * fcw[HID + ln];
#pragma unroll
  for (int o = 32; o > 0; o >>= 1) v += __shfl_xor(v, o);
  if (ln == 0) out[g] = v + fcb[0];
}

extern "C" void kernel_launch(void* const* d_in, const int* in_sizes, int n_in,
                              void* d_out, int out_size, void* d_ws, size_t ws_size,
                              hipStream_t stream)
{
  const float* x    = (const float*)d_in[0];
  const int*   ei   = (const int*)d_in[1];
  const int*   batch= (const int*)d_in[2];
  const float* W1   = (const float*)d_in[3];
  const float* as1  = (const float*)d_in[4];
  const float* ad1  = (const float*)d_in[5];
  const float* b1   = (const float*)d_in[6];
  const float* W2   = (const float*)d_in[7];
  const float* as2  = (const float*)d_in[8];
  const float* ad2  = (const float*)d_in[9];
  const float* b2   = (const float*)d_in[10];
  const float* fcw  = (const float*)d_in[11];
  const float* fcb  = (const float*)d_in[12];
  float* out = (float*)d_out;

  float* h        = (float*)d_ws;                  // NN*HID
  float* act      = h + (size_t)NN * HID;          // NN*HID
  float* a_s      = act + (size_t)NN * HID;        // NN
  float* a_d      = a_s + NN;                      // NN
  unsigned* deg   = (unsigned*)(a_d + NN);         // NN
  unsigned* rowptr= deg + NN;                      // NN
  unsigned* bcnt  = rowptr + NN;                   // NBKT (pad 1024)
  unsigned* boff  = bcnt + 1024;                   // NBKT (pad 1024)
  unsigned* bcur  = boff + 1024;                   // NBKT (pad 1024)
  int* es         = (int*)(bcur + 1024);           // ET
  unsigned* gmax  = (unsigned*)(es + ET);          // NG*HID
  float* gsum     = (float*)(gmax + NG * HID);     // NG*HID
  unsigned* cnt   = (unsigned*)(gsum + NG * HID);  // NG
  // pairs staging aliases h/act (13.6MB <= 51.2MB); consumed before k_node1 writes h
  int2* pairs     = (int2*)h;

  const int egrid = (ET + 255) / 256;

  // ---- CSR build (topology shared by both layers) ----
  hipMemsetAsync(bcnt, 0, sizeof(unsigned) * 1024, stream);
  k_bhist<<<512, 256, 0, stream>>>(ei, bcnt);
  k_bscan<<<1, 64, 0, stream>>>(bcnt, boff, bcur);
  k_bscatter<<<egrid, 256, 0, stream>>>(ei, bcur, pairs);
  k_bcsr<<<NBKT, 256, 0, stream>>>(pairs, bcnt, boff, rowptr, deg, es);

  // ---- layer 1 ----
  k_node1<<<NN / 4, 256, 0, stream>>>(x, W1, as1, ad1, h, a_s, a_d);
  k_gather<<<NN / 4, 256, 0, stream>>>(es, rowptr, deg, a_s, a_d, h, b1, act);

  // ---- layer 2 ----
  k_node2<<<NN / 4, 256, 0, stream>>>(act, W2, as2, ad2, h, a_s, a_d);
  k_gather<<<NN / 4, 256, 0, stream>>>(es, rowptr, deg, a_s, a_d, h, b2, act);

  // ---- pooling + head ----
  hipMemsetAsync(gmax, 0, sizeof(unsigned) * NG * HID, stream);
  hipMemsetAsync(gsum, 0, sizeof(float) * NG * HID, stream);
  hipMemsetAsync(cnt,  0, sizeof(unsigned) * NG, stream);
  k_pool<<<(NN + 255) / 256, 256, 0, stream>>>(act, batch, gmax, gsum, cnt);
  k_final<<<NG / 4, 256, 0, stream>>>(gmax, gsum, cnt, fcw, fcb, out);
}

// Round 4
// 409.955 us; speedup vs baseline: 2.0351x; 2.0351x over previous
//
#include <hip/hip_runtime.h>

static constexpr int NN   = 100000;   // nodes
static constexpr int NE   = 1600000;  // edges (without self loops)
static constexpr int ET   = NE + NN;  // edges + self loops
static constexpr int NG   = 512;      // graphs
static constexpr int INF_ = 16;
static constexpr int HID  = 64;
static constexpr int BKT_SH = 7;                       // 128 nodes / bucket
static constexpr int NBKT = (NN + 127) / 128;          // 782 buckets
static constexpr int NCH  = 256;                       // edge chunks (counting sort)
static constexpr int CHUNK = (ET + NCH - 1) / NCH;     // 6641 edges / chunk
static constexpr int M_   = NBKT * NCH;                // counts matrix, 200192
static constexpr int SBLK = (M_ + 1023) / 1024;        // scan blocks (196)
#define NEG_SLOPE 0.2f

__device__ __forceinline__ float lrelu(float x) { return x > 0.f ? x : NEG_SLOPE * x; }

// ---------- layer-1 node transform: h = relu(x) @ W1, a_src/a_dst dots ----------
__global__ __launch_bounds__(256) void k_node1(
    const float* __restrict__ x, const float* __restrict__ W,
    const float* __restrict__ atts, const float* __restrict__ attd,
    float* __restrict__ h, float* __restrict__ a_s, float* __restrict__ a_d)
{
  __shared__ float Ws[INF_][HID];
  __shared__ float xs[4][INF_];
  const int tid = threadIdx.x;
  for (int i = tid; i < INF_ * HID; i += 256) Ws[i / HID][i % HID] = W[i];
  const int wv = tid >> 6, ln = tid & 63;
  const int n = blockIdx.x * 4 + wv;
  if (ln < INF_) {
    float v = x[n * INF_ + ln];
    xs[wv][ln] = v > 0.f ? v : 0.f;
  }
  __syncthreads();
  float acc = 0.f;
#pragma unroll
  for (int k = 0; k < INF_; ++k) acc += xs[wv][k] * Ws[k][ln];
  h[n * HID + ln] = acc;
  float as = acc * atts[ln], ad = acc * attd[ln];
#pragma unroll
  for (int o = 32; o > 0; o >>= 1) { as += __shfl_xor(as, o); ad += __shfl_xor(ad, o); }
  if (ln == 0) { a_s[n] = as; a_d[n] = ad; }
}

// ---------- layer-2 node transform: h2 = act1 @ W2 (act1 already relu'd) ----------
__global__ __launch_bounds__(256) void k_node2(
    const float* __restrict__ act, const float* __restrict__ W,
    const float* __restrict__ atts, const float* __restrict__ attd,
    float* __restrict__ h, float* __restrict__ a_s, float* __restrict__ a_d)
{
  __shared__ float Ws[HID][HID];   // 16 KB
  __shared__ float xs[4][HID];
  const int tid = threadIdx.x;
  for (int i = tid; i < HID * HID; i += 256) Ws[i / HID][i % HID] = W[i];
  const int wv = tid >> 6, ln = tid & 63;
  const int n = blockIdx.x * 4 + wv;
  xs[wv][ln] = act[n * HID + ln];
  __syncthreads();
  float acc = 0.f;
#pragma unroll
  for (int k = 0; k < HID; ++k) acc += xs[wv][k] * Ws[k][ln];
  h[n * HID + ln] = acc;
  float as = acc * atts[ln], ad = acc * attd[ln];
#pragma unroll
  for (int o = 32; o > 0; o >>= 1) { as += __shfl_xor(as, o); ad += __shfl_xor(ad, o); }
  if (ln == 0) { a_s[n] = as; a_d[n] = ad; }
}

// ---------- counting sort pass A: per-chunk bucket histogram ----------
__global__ __launch_bounds__(256) void k_cnt(const int* __restrict__ ei,
                                             unsigned* __restrict__ counts)
{
  __shared__ unsigned lc[NBKT];
  for (int i = threadIdx.x; i < NBKT; i += 256) lc[i] = 0;
  __syncthreads();
  const int b = blockIdx.x;
  const int beg = b * CHUNK, end = min(ET, beg + CHUNK);
  for (int e = beg + threadIdx.x; e < end; e += 256) {
    int d = (e < NE) ? ei[NE + e] : e - NE;
    atomicAdd(&lc[d >> BKT_SH], 1u);
  }
  __syncthreads();
  for (int k = threadIdx.x; k < NBKT; k += 256) counts[k * NCH + b] = lc[k];
}

// ---------- scan pass 1: 1024-elem block sums over counts ----------
__global__ __launch_bounds__(256) void k_scan1(const unsigned* __restrict__ counts,
                                               unsigned* __restrict__ bsums)
{
  __shared__ unsigned red[4];
  const int t = threadIdx.x;
  const int base = blockIdx.x * 1024 + t * 4;
  unsigned s = 0;
#pragma unroll
  for (int k = 0; k < 4; ++k) { int i = base + k; if (i < M_) s += counts[i]; }
#pragma unroll
  for (int o = 32; o > 0; o >>= 1) s += __shfl_xor(s, o);
  if ((t & 63) == 0) red[t >> 6] = s;
  __syncthreads();
  if (t == 0) bsums[blockIdx.x] = red[0] + red[1] + red[2] + red[3];
}

// ---------- scan pass 2: exclusive scan of block sums (single wave) ----------
__global__ __launch_bounds__(64) void k_scan2(unsigned* __restrict__ bsums)
{
  const int ln = threadIdx.x;
  unsigned carry = 0;
  for (int base = 0; base < SBLK; base += 64) {
    int i = base + ln;
    unsigned orig = (i < SBLK) ? bsums[i] : 0;
    unsigned v = orig;
#pragma unroll
    for (int o = 1; o < 64; o <<= 1) { unsigned tv = __shfl_up(v, o); if (ln >= o) v += tv; }
    if (i < SBLK) bsums[i] = carry + v - orig;
    carry += __shfl(v, 63);
  }
}

// ---------- scan pass 3: add-back, exclusive scan in place ----------
__global__ __launch_bounds__(256) void k_scan3(unsigned* __restrict__ counts,
                                               const unsigned* __restrict__ bsums)
{
  __shared__ unsigned wsum[4];
  const int t = threadIdx.x;
  const int base = blockIdx.x * 1024 + t * 4;
  unsigned d[4]; unsigned s = 0;
#pragma unroll
  for (int k = 0; k < 4; ++k) { int i = base + k; d[k] = (i < M_) ? counts[i] : 0; s += d[k]; }
  unsigned v = s;
#pragma unroll
  for (int o = 1; o < 64; o <<= 1) { unsigned tv = __shfl_up(v, o); if ((t & 63) >= o) v += tv; }
  if ((t & 63) == 63) wsum[t >> 6] = v;
  __syncthreads();
  unsigned woff = 0;
  for (int w = 0; w < (t >> 6); ++w) woff += wsum[w];
  unsigned excl = woff + (v - s) + bsums[blockIdx.x];
#pragma unroll
  for (int k = 0; k < 4; ++k) {
    int i = base + k;
    if (i < M_) counts[i] = excl;
    excl += d[k];
  }
}

// ---------- bucket metadata from scanned matrix ----------
__global__ __launch_bounds__(256) void k_bmeta(const unsigned* __restrict__ S,
                                               unsigned* __restrict__ boff,
                                               unsigned* __restrict__ bcnt)
{
  int k = blockIdx.x * 256 + threadIdx.x;
  if (k >= NBKT) return;
  unsigned lo = S[k * NCH];
  unsigned hi = (k + 1 < NBKT) ? S[(k + 1) * NCH] : (unsigned)ET;
  boff[k] = lo; bcnt[k] = hi - lo;
}

// ---------- counting sort pass C: place pairs (LDS cursors, no global atomics) ----------
__global__ __launch_bounds__(256) void k_place(const int* __restrict__ ei,
                                               const unsigned* __restrict__ S,
                                               int2* __restrict__ pairs)
{
  __shared__ unsigned cur[NBKT];
  const int b = blockIdx.x;
  for (int k = threadIdx.x; k < NBKT; k += 256) cur[k] = S[k * NCH + b];
  __syncthreads();
  const int beg = b * CHUNK, end = min(ET, beg + CHUNK);
  for (int e = beg + threadIdx.x; e < end; e += 256) {
    int s, d;
    if (e < NE) { s = ei[e]; d = ei[NE + e]; } else { s = d = e - NE; }
    unsigned pos = atomicAdd(&cur[d >> BKT_SH], 1u);
    pairs[pos] = make_int2(s, d);
  }
}

// ---------- per-bucket fine CSR build (all in LDS, one block per bucket) ----------
__global__ __launch_bounds__(256) void k_bcsr(const int2* __restrict__ pairs,
                                              const unsigned* __restrict__ bcnt,
                                              const unsigned* __restrict__ boff,
                                              unsigned* __restrict__ rowptr,
                                              unsigned* __restrict__ deg,
                                              int* __restrict__ es)
{
  __shared__ unsigned cnt[128], cur[128], wtot[2];
  const int b = blockIdx.x, t = threadIdx.x;
  const unsigned base = boff[b], m = bcnt[b];
  if (t < 128) cnt[t] = 0;
  __syncthreads();
  for (unsigned j = t; j < m; j += 256)
    atomicAdd(&cnt[pairs[base + j].y & 127], 1u);
  __syncthreads();
  unsigned c = 0, v = 0;
  if (t < 128) {
    c = cnt[t]; v = c;
    const int ln = t & 63;
#pragma unroll
    for (int o = 1; o < 64; o <<= 1) { unsigned tv = __shfl_up(v, o); if (ln >= o) v += tv; }
    if (ln == 63) wtot[t >> 6] = v;
  }
  __syncthreads();
  if (t < 128) {
    unsigned excl = v - c + ((t >= 64) ? wtot[0] : 0);
    cur[t] = excl;
    int node = (b << BKT_SH) + t;
    if (node < NN) { rowptr[node] = base + excl; deg[node] = c; }
  }
  __syncthreads();
  for (unsigned j = t; j < m; j += 256) {
    int2 p = pairs[base + j];
    unsigned pos = atomicAdd(&cur[p.y & 127], 1u);
    es[base + pos] = p.x;
  }
}

// ---------- gather-style GAT aggregate: wave per dst node, no atomics ----------
__global__ __launch_bounds__(256) void k_gather(
    const int* __restrict__ es, const unsigned* __restrict__ rowptr,
    const unsigned* __restrict__ deg, const float* __restrict__ a_s,
    const float* __restrict__ a_d, const float* __restrict__ h,
    const float* __restrict__ bias, float* __restrict__ act)
{
  const int wv = threadIdx.x >> 6, ln = threadIdx.x & 63;
  const int n = blockIdx.x * 4 + wv;
  const unsigned beg = rowptr[n];
  const unsigned end = beg + deg[n];
  const float ad = a_d[n];
  // phase 1: segment max (lane-parallel over edges)
  float m = -1e30f;
  for (unsigned j = beg + ln; j < end; j += 64) {
    int s = es[j];
    m = fmaxf(m, lrelu(a_s[s] + ad));
  }
#pragma unroll
  for (int o = 32; o > 0; o >>= 1) m = fmaxf(m, __shfl_xor(m, o));
  // phase 2: serial over edges, lane-parallel over features
  float acc = 0.f, den = 0.f;
  unsigned j = beg;
  for (; j + 1 < end; j += 2) {
    int s0 = es[j], s1 = es[j + 1];
    float e0 = __expf(lrelu(a_s[s0] + ad) - m);
    float e1 = __expf(lrelu(a_s[s1] + ad) - m);
    float h0 = h[(size_t)s0 * HID + ln];
    float h1 = h[(size_t)s1 * HID + ln];
    den += e0 + e1;
    acc += h0 * e0 + h1 * e1;
  }
  if (j < end) {
    int s0 = es[j];
    float e0 = __expf(lrelu(a_s[s0] + ad) - m);
    den += e0;
    acc += h[(size_t)s0 * HID + ln] * e0;
  }
  float v = acc / (den + 1e-16f) + bias[ln];
  act[n * HID + ln] = v > 0.f ? v : 0.f;
}

// ---------- pooling: per-graph max/sum over finalized act2 ----------
__global__ __launch_bounds__(256) void k_pool(
    const float* __restrict__ act, const int* __restrict__ batch,
    unsigned* __restrict__ gmax, float* __restrict__ gsum, unsigned* __restrict__ cnt)
{
  const int wv = threadIdx.x >> 6, ln = threadIdx.x & 63;
  const int base = (blockIdx.x * 4 + wv) * 64;
  if (base >= NN) return;
  const int end = min(NN, base + 64);
  float rmax = 0.f, rsum = 0.f;
  int cg = batch[base], run = 0;
  for (int n = base; n < end; ++n) {
    int g = batch[n];
    if (g != cg) {
      atomicMax(&gmax[cg * HID + ln], __float_as_uint(rmax));  // relu -> >=0
      unsafeAtomicAdd(&gsum[cg * HID + ln], rsum);
      if (ln == 0) atomicAdd(&cnt[cg], (unsigned)run);
      rmax = 0.f; rsum = 0.f; run = 0; cg = g;
    }
    float v = act[n * HID + ln];
    rmax = fmaxf(rmax, v); rsum += v; ++run;
  }
  atomicMax(&gmax[cg * HID + ln], __float_as_uint(rmax));
  unsafeAtomicAdd(&gsum[cg * HID + ln], rsum);
  if (ln == 0) atomicAdd(&cnt[cg], (unsigned)run);
}

// ---------- head: [gmax | gmean] @ fc_w + fc_b ----------
__global__ __launch_bounds__(256) void k_final(
    const unsigned* __restrict__ gmax, const float* __restrict__ gsum,
    const unsigned* __restrict__ cnt, const float* __restrict__ fcw,
    const float* __restrict__ fcb, float* __restrict__ out)
{
  const int wv = threadIdx.x >> 6, ln = threadIdx.x & 63;
  const int g = blockIdx.x * 4 + wv;
  if (g >= NG) return;
  float c = (float)cnt[g];
  float mx = __uint_as_float(gmax[g * HID + ln]);
  float mean = gsum[g * HID + ln] / fmaxf(c, 1.f);
  float v = mx * fcw[ln] + mean * fcw[HID + ln];
#pragma unroll
  for (int o = 32; o > 0; o >>= 1) v += __shfl_xor(v, o);
  if (ln == 0) out[g] = v + fcb[0];
}

extern "C" void kernel_launch(void* const* d_in, const int* in_sizes, int n_in,
                              void* d_out, int out_size, void* d_ws, size_t ws_size,
                              hipStream_t stream)
{
  const float* x    = (const float*)d_in[0];
  const int*   ei   = (const int*)d_in[1];
  const int*   batch= (const int*)d_in[2];
  const float* W1   = (const float*)d_in[3];
  const float* as1  = (const float*)d_in[4];
  const float* ad1  = (const float*)d_in[5];
  const float* b1   = (const float*)d_in[6];
  const float* W2   = (const float*)d_in[7];
  const float* as2  = (const float*)d_in[8];
  const float* ad2  = (const float*)d_in[9];
  const float* b2   = (const float*)d_in[10];
  const float* fcw  = (const float*)d_in[11];
  const float* fcb  = (const float*)d_in[12];
  float* out = (float*)d_out;

  float* h        = (float*)d_ws;                  // NN*HID
  float* act      = h + (size_t)NN * HID;          // NN*HID
  float* a_s      = act + (size_t)NN * HID;        // NN
  float* a_d      = a_s + NN;                      // NN
  unsigned* deg   = (unsigned*)(a_d + NN);         // NN
  unsigned* rowptr= deg + NN;                      // NN
  unsigned* bcnt  = rowptr + NN;                   // NBKT (pad 1024)
  unsigned* boff  = bcnt + 1024;                   // NBKT (pad 1024)
  unsigned* counts= boff + 1024;                   // M_ (pad to 200704)
  unsigned* bsums = counts + 200704;               // SBLK (pad 256)
  int* es         = (int*)(bsums + 256);           // ET
  unsigned* gmax  = (unsigned*)(es + ET);          // NG*HID
  float* gsum     = (float*)(gmax + NG * HID);     // NG*HID
  unsigned* cnt   = (unsigned*)(gsum + NG * HID);  // NG
  // pairs staging aliases h/act (13.6MB <= 51.2MB); consumed before k_node1 writes h
  int2* pairs     = (int2*)h;

  // ---- CSR build via contention-free counting sort (topology shared) ----
  k_cnt  <<<NCH, 256, 0, stream>>>(ei, counts);
  k_scan1<<<SBLK, 256, 0, stream>>>(counts, bsums);
  k_scan2<<<1, 64, 0, stream>>>(bsums);
  k_scan3<<<SBLK, 256, 0, stream>>>(counts, bsums);
  k_bmeta<<<(NBKT + 255) / 256, 256, 0, stream>>>(counts, boff, bcnt);
  k_place<<<NCH, 256, 0, stream>>>(ei, counts, pairs);
  k_bcsr <<<NBKT, 256, 0, stream>>>(pairs, bcnt, boff, rowptr, deg, es);

  // ---- layer 1 ----
  k_node1<<<NN / 4, 256, 0, stream>>>(x, W1, as1, ad1, h, a_s, a_d);
  k_gather<<<NN / 4, 256, 0, stream>>>(es, rowptr, deg, a_s, a_d, h, b1, act);

  // ---- layer 2 ----
  k_node2<<<NN / 4, 256, 0, stream>>>(act, W2, as2, ad2, h, a_s, a_d);
  k_gather<<<NN / 4, 256, 0, stream>>>(es, rowptr, deg, a_s, a_d, h, b2, act);

  // ---- pooling + head ----
  hipMemsetAsync(gmax, 0, sizeof(unsigned) * NG * HID, stream);
  hipMemsetAsync(gsum, 0, sizeof(float) * NG * HID, stream);
  hipMemsetAsync(cnt,  0, sizeof(unsigned) * NG, stream);
  k_pool<<<(NN + 255) / 256, 256, 0, stream>>>(act, batch, gmax, gsum, cnt);
  k_final<<<NG / 4, 256, 0, stream>>>(gmax, gsum, cnt, fcw, fcb, out);
}

// Round 5
// 362.153 us; speedup vs baseline: 2.3037x; 1.1320x over previous
//
#include <hip/hip_runtime.h>

static constexpr int NN   = 100000;   // nodes
static constexpr int NE   = 1600000;  // edges (without self loops)
static constexpr int ET   = NE + NN;  // edges + self loops
static constexpr int NG   = 512;      // graphs
static constexpr int INF_ = 16;
static constexpr int HID  = 64;
static constexpr int BKT_SH = 7;                       // 128 nodes / bucket
static constexpr int NBKT = (NN + 127) / 128;          // 782 buckets
static constexpr int NCH  = 256;                       // edge chunks (counting sort)
static constexpr int CHUNK = (ET + NCH - 1) / NCH;     // 6641 edges / chunk
static constexpr int M_   = NBKT * NCH;                // counts matrix, 200192
static constexpr int SBLK = (M_ + 1023) / 1024;        // scan blocks (196)
#define NEG_SLOPE 0.2f

__device__ __forceinline__ float lrelu(float x) { return x > 0.f ? x : NEG_SLOPE * x; }

// ---------- layer-1 node transform: h = relu(x) @ W1, a_src/a_dst dots ----------
__global__ __launch_bounds__(256) void k_node1(
    const float* __restrict__ x, const float* __restrict__ W,
    const float* __restrict__ atts, const float* __restrict__ attd,
    float* __restrict__ h, float* __restrict__ a_s, float* __restrict__ a_d)
{
  __shared__ float Ws[INF_][HID];
  __shared__ float xs[4][INF_];
  const int tid = threadIdx.x;
  for (int i = tid; i < INF_ * HID; i += 256) Ws[i / HID][i % HID] = W[i];
  const int wv = tid >> 6, ln = tid & 63;
  const int n = blockIdx.x * 4 + wv;
  if (ln < INF_) {
    float v = x[n * INF_ + ln];
    xs[wv][ln] = v > 0.f ? v : 0.f;
  }
  __syncthreads();
  float acc = 0.f;
#pragma unroll
  for (int k = 0; k < INF_; ++k) acc += xs[wv][k] * Ws[k][ln];
  h[n * HID + ln] = acc;
  float as = acc * atts[ln], ad = acc * attd[ln];
#pragma unroll
  for (int o = 32; o > 0; o >>= 1) { as += __shfl_xor(as, o); ad += __shfl_xor(ad, o); }
  if (ln == 0) { a_s[n] = as; a_d[n] = ad; }
}

// ---------- layer-2 node transform: h2 = act1 @ W2 (act1 already relu'd) ----------
__global__ __launch_bounds__(256) void k_node2(
    const float* __restrict__ act, const float* __restrict__ W,
    const float* __restrict__ atts, const float* __restrict__ attd,
    float* __restrict__ h, float* __restrict__ a_s, float* __restrict__ a_d)
{
  __shared__ float Ws[HID][HID];   // 16 KB
  __shared__ float xs[4][HID];
  const int tid = threadIdx.x;
  for (int i = tid; i < HID * HID; i += 256) Ws[i / HID][i % HID] = W[i];
  const int wv = tid >> 6, ln = tid & 63;
  const int n = blockIdx.x * 4 + wv;
  xs[wv][ln] = act[n * HID + ln];
  __syncthreads();
  float acc = 0.f;
#pragma unroll
  for (int k = 0; k < HID; ++k) acc += xs[wv][k] * Ws[k][ln];
  h[n * HID + ln] = acc;
  float as = acc * atts[ln], ad = acc * attd[ln];
#pragma unroll
  for (int o = 32; o > 0; o >>= 1) { as += __shfl_xor(as, o); ad += __shfl_xor(ad, o); }
  if (ln == 0) { a_s[n] = as; a_d[n] = ad; }
}

// ---------- counting sort pass A: per-chunk bucket histogram ----------
__global__ __launch_bounds__(256) void k_cnt(const int* __restrict__ ei,
                                             unsigned* __restrict__ counts)
{
  __shared__ unsigned lc[NBKT];
  for (int i = threadIdx.x; i < NBKT; i += 256) lc[i] = 0;
  __syncthreads();
  const int b = blockIdx.x;
  const int beg = b * CHUNK, end = min(ET, beg + CHUNK);
  for (int e = beg + threadIdx.x; e < end; e += 256) {
    int d = (e < NE) ? ei[NE + e] : e - NE;
    atomicAdd(&lc[d >> BKT_SH], 1u);
  }
  __syncthreads();
  for (int k = threadIdx.x; k < NBKT; k += 256) counts[k * NCH + b] = lc[k];
}

// ---------- scan pass 1: 1024-elem block sums over counts ----------
__global__ __launch_bounds__(256) void k_scan1(const unsigned* __restrict__ counts,
                                               unsigned* __restrict__ bsums)
{
  __shared__ unsigned red[4];
  const int t = threadIdx.x;
  const int base = blockIdx.x * 1024 + t * 4;
  unsigned s = 0;
#pragma unroll
  for (int k = 0; k < 4; ++k) { int i = base + k; if (i < M_) s += counts[i]; }
#pragma unroll
  for (int o = 32; o > 0; o >>= 1) s += __shfl_xor(s, o);
  if ((t & 63) == 0) red[t >> 6] = s;
  __syncthreads();
  if (t == 0) bsums[blockIdx.x] = red[0] + red[1] + red[2] + red[3];
}

// ---------- scan pass 2: exclusive scan of block sums (single wave) ----------
__global__ __launch_bounds__(64) void k_scan2(unsigned* __restrict__ bsums)
{
  const int ln = threadIdx.x;
  unsigned carry = 0;
  for (int base = 0; base < SBLK; base += 64) {
    int i = base + ln;
    unsigned orig = (i < SBLK) ? bsums[i] : 0;
    unsigned v = orig;
#pragma unroll
    for (int o = 1; o < 64; o <<= 1) { unsigned tv = __shfl_up(v, o); if (ln >= o) v += tv; }
    if (i < SBLK) bsums[i] = carry + v - orig;
    carry += __shfl(v, 63);
  }
}

// ---------- scan pass 3: add-back, exclusive scan in place ----------
__global__ __launch_bounds__(256) void k_scan3(unsigned* __restrict__ counts,
                                               const unsigned* __restrict__ bsums)
{
  __shared__ unsigned wsum[4];
  const int t = threadIdx.x;
  const int base = blockIdx.x * 1024 + t * 4;
  unsigned d[4]; unsigned s = 0;
#pragma unroll
  for (int k = 0; k < 4; ++k) { int i = base + k; d[k] = (i < M_) ? counts[i] : 0; s += d[k]; }
  unsigned v = s;
#pragma unroll
  for (int o = 1; o < 64; o <<= 1) { unsigned tv = __shfl_up(v, o); if ((t & 63) >= o) v += tv; }
  if ((t & 63) == 63) wsum[t >> 6] = v;
  __syncthreads();
  unsigned woff = 0;
  for (int w = 0; w < (t >> 6); ++w) woff += wsum[w];
  unsigned excl = woff + (v - s) + bsums[blockIdx.x];
#pragma unroll
  for (int k = 0; k < 4; ++k) {
    int i = base + k;
    if (i < M_) counts[i] = excl;
    excl += d[k];
  }
}

// ---------- bucket metadata from scanned matrix ----------
__global__ __launch_bounds__(256) void k_bmeta(const unsigned* __restrict__ S,
                                               unsigned* __restrict__ boff,
                                               unsigned* __restrict__ bcnt)
{
  int k = blockIdx.x * 256 + threadIdx.x;
  if (k >= NBKT) return;
  unsigned lo = S[k * NCH];
  unsigned hi = (k + 1 < NBKT) ? S[(k + 1) * NCH] : (unsigned)ET;
  boff[k] = lo; bcnt[k] = hi - lo;
}

// ---------- counting sort pass C: place pairs (LDS cursors, no global atomics) ----------
__global__ __launch_bounds__(256) void k_place(const int* __restrict__ ei,
                                               const unsigned* __restrict__ S,
                                               int2* __restrict__ pairs)
{
  __shared__ unsigned cur[NBKT];
  const int b = blockIdx.x;
  for (int k = threadIdx.x; k < NBKT; k += 256) cur[k] = S[k * NCH + b];
  __syncthreads();
  const int beg = b * CHUNK, end = min(ET, beg + CHUNK);
  for (int e = beg + threadIdx.x; e < end; e += 256) {
    int s, d;
    if (e < NE) { s = ei[e]; d = ei[NE + e]; } else { s = d = e - NE; }
    unsigned pos = atomicAdd(&cur[d >> BKT_SH], 1u);
    pairs[pos] = make_int2(s, d);
  }
}

// ---------- per-bucket fine CSR build (all in LDS, one block per bucket) ----------
__global__ __launch_bounds__(256) void k_bcsr(const int2* __restrict__ pairs,
                                              const unsigned* __restrict__ bcnt,
                                              const unsigned* __restrict__ boff,
                                              unsigned* __restrict__ rowptr,
                                              unsigned* __restrict__ deg,
                                              int* __restrict__ es)
{
  __shared__ unsigned cnt[128], cur[128], wtot[2];
  const int b = blockIdx.x, t = threadIdx.x;
  const unsigned base = boff[b], m = bcnt[b];
  if (t < 128) cnt[t] = 0;
  __syncthreads();
  for (unsigned j = t; j < m; j += 256)
    atomicAdd(&cnt[pairs[base + j].y & 127], 1u);
  __syncthreads();
  unsigned c = 0, v = 0;
  if (t < 128) {
    c = cnt[t]; v = c;
    const int ln = t & 63;
#pragma unroll
    for (int o = 1; o < 64; o <<= 1) { unsigned tv = __shfl_up(v, o); if (ln >= o) v += tv; }
    if (ln == 63) wtot[t >> 6] = v;
  }
  __syncthreads();
  if (t < 128) {
    unsigned excl = v - c + ((t >= 64) ? wtot[0] : 0);
    cur[t] = excl;
    int node = (b << BKT_SH) + t;
    if (node < NN) { rowptr[node] = base + excl; deg[node] = c; }
  }
  __syncthreads();
  for (unsigned j = t; j < m; j += 256) {
    int2 p = pairs[base + j];
    unsigned pos = atomicAdd(&cur[p.y & 127], 1u);
    es[base + pos] = p.x;
  }
}

// ---------- gather-style GAT aggregate: wave per dst node ----------
// phase 2: 16 edges in parallel, 4 lanes (16 feats each) per edge -> 8x MLP,
// expf computed once per edge (not 64x).
__global__ __launch_bounds__(256) void k_gather(
    const int* __restrict__ es, const unsigned* __restrict__ rowptr,
    const unsigned* __restrict__ deg, const float* __restrict__ a_s,
    const float* __restrict__ a_d, const float* __restrict__ h,
    const float* __restrict__ bias, float* __restrict__ act)
{
  const int wv = threadIdx.x >> 6, ln = threadIdx.x & 63;
  const int n = blockIdx.x * 4 + wv;
  const unsigned beg = rowptr[n];
  const unsigned end = beg + deg[n];
  const float ad = a_d[n];
  // phase 1: segment max (lane-parallel over edges)
  float m = -1e30f;
  for (unsigned j = beg + ln; j < end; j += 64) {
    m = fmaxf(m, lrelu(a_s[es[j]] + ad));
  }
#pragma unroll
  for (int o = 32; o > 0; o >>= 1) m = fmaxf(m, __shfl_xor(m, o));

  const int e16 = ln >> 2, q = ln & 3;
  float a[16];
#pragma unroll
  for (int k = 0; k < 16; ++k) a[k] = 0.f;
  float denp = 0.f;

  for (unsigned c = beg; c < end; c += 16) {
    // stage 16 edges in lanes 0..15
    int s_st = 0; float ev_st = 0.f;
    {
      unsigned j = c + (unsigned)ln;
      if (ln < 16 && j < end) {
        s_st = es[j];
        ev_st = __expf(lrelu(a_s[s_st] + ad) - m);
        denp += ev_st;
      }
    }
    int   s  = __shfl(s_st, e16);
    float ev = __shfl(ev_st, e16);
    if (c + (unsigned)e16 < end) {
      const float4* hp = (const float4*)(h + (size_t)s * HID + q * 16);
      float4 h0 = hp[0], h1 = hp[1], h2 = hp[2], h3 = hp[3];
      a[0]  += ev * h0.x; a[1]  += ev * h0.y; a[2]  += ev * h0.z; a[3]  += ev * h0.w;
      a[4]  += ev * h1.x; a[5]  += ev * h1.y; a[6]  += ev * h1.z; a[7]  += ev * h1.w;
      a[8]  += ev * h2.x; a[9]  += ev * h2.y; a[10] += ev * h2.z; a[11] += ev * h2.w;
      a[12] += ev * h3.x; a[13] += ev * h3.y; a[14] += ev * h3.z; a[15] += ev * h3.w;
    }
  }
  // reduce den over wave (lanes >=16 hold 0)
#pragma unroll
  for (int o = 32; o > 0; o >>= 1) denp += __shfl_xor(denp, o);
  // reduce acc across the 16 edge-groups (strides 4..32)
#pragma unroll
  for (int o = 4; o < 64; o <<= 1) {
#pragma unroll
    for (int k = 0; k < 16; ++k) a[k] += __shfl_xor(a[k], o);
  }
  if (ln < 4) {   // lane ln holds features [ln*16, ln*16+16)
    float inv = 1.f / (denp + 1e-16f);
    float4* op = (float4*)(act + (size_t)n * HID + ln * 16);
    const float4* bp = (const float4*)(bias + ln * 16);
#pragma unroll
    for (int k = 0; k < 4; ++k) {
      float4 b4 = bp[k];
      float4 v;
      v.x = a[4 * k + 0] * inv + b4.x;
      v.y = a[4 * k + 1] * inv + b4.y;
      v.z = a[4 * k + 2] * inv + b4.z;
      v.w = a[4 * k + 3] * inv + b4.w;
      v.x = v.x > 0.f ? v.x : 0.f;
      v.y = v.y > 0.f ? v.y : 0.f;
      v.z = v.z > 0.f ? v.z : 0.f;
      v.w = v.w > 0.f ? v.w : 0.f;
      op[k] = v;
    }
  }
}

// ---------- pooling: per-graph max/sum over finalized act2 ----------
__global__ __launch_bounds__(256) void k_pool(
    const float* __restrict__ act, const int* __restrict__ batch,
    unsigned* __restrict__ gmax, float* __restrict__ gsum, unsigned* __restrict__ cnt)
{
  const int wv = threadIdx.x >> 6, ln = threadIdx.x & 63;
  const int base = (blockIdx.x * 4 + wv) * 64;
  if (base >= NN) return;
  const int end = min(NN, base + 64);
  float rmax = 0.f, rsum = 0.f;
  int cg = batch[base], run = 0;
  for (int n = base; n < end; ++n) {
    int g = batch[n];
    if (g != cg) {
      atomicMax(&gmax[cg * HID + ln], __float_as_uint(rmax));  // relu -> >=0
      unsafeAtomicAdd(&gsum[cg * HID + ln], rsum);
      if (ln == 0) atomicAdd(&cnt[cg], (unsigned)run);
      rmax = 0.f; rsum = 0.f; run = 0; cg = g;
    }
    float v = act[n * HID + ln];
    rmax = fmaxf(rmax, v); rsum += v; ++run;
  }
  atomicMax(&gmax[cg * HID + ln], __float_as_uint(rmax));
  unsafeAtomicAdd(&gsum[cg * HID + ln], rsum);
  if (ln == 0) atomicAdd(&cnt[cg], (unsigned)run);
}

// ---------- head: [gmax | gmean] @ fc_w + fc_b ----------
__global__ __launch_bounds__(256) void k_final(
    const unsigned* __restrict__ gmax, const float* __restrict__ gsum,
    const unsigned* __restrict__ cnt, const float* __restrict__ fcw,
    const float* __restrict__ fcb, float* __restrict__ out)
{
  const int wv = threadIdx.x >> 6, ln = threadIdx.x & 63;
  const int g = blockIdx.x * 4 + wv;
  if (g >= NG) return;
  float c = (float)cnt[g];
  float mx = __uint_as_float(gmax[g * HID + ln]);
  float mean = gsum[g * HID + ln] / fmaxf(c, 1.f);
  float v = mx * fcw[ln] + mean * fcw[HID + ln];
#pragma unroll
  for (int o = 32; o > 0; o >>= 1) v += __shfl_xor(v, o);
  if (ln == 0) out[g] = v + fcb[0];
}

extern "C" void kernel_launch(void* const* d_in, const int* in_sizes, int n_in,
                              void* d_out, int out_size, void* d_ws, size_t ws_size,
                              hipStream_t stream)
{
  const float* x    = (const float*)d_in[0];
  const int*   ei   = (const int*)d_in[1];
  const int*   batch= (const int*)d_in[2];
  const float* W1   = (const float*)d_in[3];
  const float* as1  = (const float*)d_in[4];
  const float* ad1  = (const float*)d_in[5];
  const float* b1   = (const float*)d_in[6];
  const float* W2   = (const float*)d_in[7];
  const float* as2  = (const float*)d_in[8];
  const float* ad2  = (const float*)d_in[9];
  const float* b2   = (const float*)d_in[10];
  const float* fcw  = (const float*)d_in[11];
  const float* fcb  = (const float*)d_in[12];
  float* out = (float*)d_out;

  float* h        = (float*)d_ws;                  // NN*HID
  float* act      = h + (size_t)NN * HID;          // NN*HID
  float* a_s      = act + (size_t)NN * HID;        // NN
  float* a_d      = a_s + NN;                      // NN
  unsigned* deg   = (unsigned*)(a_d + NN);         // NN
  unsigned* rowptr= deg + NN;                      // NN
  unsigned* bcnt  = rowptr + NN;                   // NBKT (pad 1024)
  unsigned* boff  = bcnt + 1024;                   // NBKT (pad 1024)
  unsigned* counts= boff + 1024;                   // M_ (pad to 200704)
  unsigned* bsums = counts + 200704;               // SBLK (pad 256)
  int* es         = (int*)(bsums + 256);           // ET
  unsigned* gmax  = (unsigned*)(es + ET);          // NG*HID
  float* gsum     = (float*)(gmax + NG * HID);     // NG*HID
  unsigned* cnt   = (unsigned*)(gsum + NG * HID);  // NG
  // pairs staging aliases h/act (13.6MB <= 51.2MB); consumed before k_node1 writes h
  int2* pairs     = (int2*)h;

  // ---- CSR build via contention-free counting sort (topology shared) ----
  k_cnt  <<<NCH, 256, 0, stream>>>(ei, counts);
  k_scan1<<<SBLK, 256, 0, stream>>>(counts, bsums);
  k_scan2<<<1, 64, 0, stream>>>(bsums);
  k_scan3<<<SBLK, 256, 0, stream>>>(counts, bsums);
  k_bmeta<<<(NBKT + 255) / 256, 256, 0, stream>>>(counts, boff, bcnt);
  k_place<<<NCH, 256, 0, stream>>>(ei, counts, pairs);
  k_bcsr <<<NBKT, 256, 0, stream>>>(pairs, bcnt, boff, rowptr, deg, es);

  // ---- layer 1 ----
  k_node1<<<NN / 4, 256, 0, stream>>>(x, W1, as1, ad1, h, a_s, a_d);
  k_gather<<<NN / 4, 256, 0, stream>>>(es, rowptr, deg, a_s, a_d, h, b1, act);

  // ---- layer 2 ----
  k_node2<<<NN / 4, 256, 0, stream>>>(act, W2, as2, ad2, h, a_s, a_d);
  k_gather<<<NN / 4, 256, 0, stream>>>(es, rowptr, deg, a_s, a_d, h, b2, act);

  // ---- pooling + head ----
  hipMemsetAsync(gmax, 0, sizeof(unsigned) * NG * HID, stream);
  hipMemsetAsync(gsum, 0, sizeof(float) * NG * HID, stream);
  hipMemsetAsync(cnt,  0, sizeof(unsigned) * NG, stream);
  k_pool<<<(NN + 255) / 256, 256, 0, stream>>>(act, batch, gmax, gsum, cnt);
  k_final<<<NG / 4, 256, 0, stream>>>(gmax, gsum, cnt, fcw, fcb, out);
}